// Round 5
// baseline (247.438 us; speedup 1.0000x reference)
//
#include <hip/hip_runtime.h>

#define DF 128
#define SCAN_B 64
#define SCAN_T 256
#define GN 64           // nodes per gather_gemm block
#define MST 272         // LDS mean-row stride bytes (17*16: 16B-aligned, 2-way banks)

typedef __attribute__((ext_vector_type(8))) short short8;
typedef __attribute__((ext_vector_type(4))) float float4v;

__device__ __forceinline__ unsigned int bf16rne(float f) {
    unsigned int u = __float_as_uint(f);
    return (u + 0x7fffu + ((u >> 16) & 1u)) >> 16;
}
__device__ __forceinline__ float bf16lo(unsigned int w) {
    return __uint_as_float(w << 16);
}
__device__ __forceinline__ float bf16hi(unsigned int w) {
    return __uint_as_float(w & 0xffff0000u);
}

// ---------------------------------------------------------------------------
// prep: fused (a) histogram of dst, (b) x fp32->bf16 cast into compact xb,
// (c) [Wl;Wr] swizzle into MFMA B-fragment order (bf16).
// Disjoint work per tid range; grid covers max(N*16, E).
// ---------------------------------------------------------------------------
__global__ __launch_bounds__(256) void sage_prep(
    const float* __restrict__ x, const int* __restrict__ dst,
    const float* __restrict__ Wl, const float* __restrict__ Wr,
    int* __restrict__ cnt, char* __restrict__ xb, uint4* __restrict__ Bf,
    int N, int E)
{
    int tid = blockIdx.x * 256 + threadIdx.x;

    if (tid < N * 16) {                      // xcast: 16 threads/row
        int n = tid >> 4;
        int c = (tid & 15) * 8;
        const float4* xp = (const float4*)&x[(size_t)n * DF + c];
        float4 a = xp[0], b = xp[1];
        uint4 o;
        o.x = bf16rne(a.x) | (bf16rne(a.y) << 16);
        o.y = bf16rne(a.z) | (bf16rne(a.w) << 16);
        o.z = bf16rne(b.x) | (bf16rne(b.y) << 16);
        o.w = bf16rne(b.z) | (bf16rne(b.w) << 16);
        *(uint4*)(xb + (size_t)n * 256 + (size_t)(tid & 15) * 16) = o;
    }

    if (tid < E) atomicAdd(&cnt[dst[tid]], 1);   // histogram

    if (tid < 4096) {                        // bprep
        int lane = tid & 63;
        int ctks = tid >> 6;
        int ks = ctks >> 3, ct = ctks & 7;
        int q = lane >> 4, m16 = lane & 15;
        int n = ct * 16 + m16;
        unsigned int w[4];
        #pragma unroll
        for (int p = 0; p < 4; ++p) {
            int k0 = ks * 32 + q * 8 + p * 2;
            float f0 = (k0 < DF) ? Wl[k0 * DF + n] : Wr[(k0 - DF) * DF + n];
            float f1 = (k0 + 1 < DF) ? Wl[(k0 + 1) * DF + n] : Wr[(k0 + 1 - DF) * DF + n];
            w[p] = bf16rne(f0) | (bf16rne(f1) << 16);
        }
        uint4 o = {w[0], w[1], w[2], w[3]};
        Bf[tid] = o;
    }
}

// ---------------------------------------------------------------------------
// hierarchical scan pass 1: per-block reduce -> blktot
// ---------------------------------------------------------------------------
__global__ __launch_bounds__(SCAN_T) void scan_reduce(
    const int* __restrict__ cnt, int* __restrict__ blktot, int N)
{
    __shared__ int sdata[SCAN_T];
    const int t = threadIdx.x, b = blockIdx.x;
    const int chunk = (N + SCAN_B * SCAN_T - 1) / (SCAN_B * SCAN_T);
    const int lo = (b * SCAN_T + t) * chunk;
    const int hi = min(lo + chunk, N);
    int total = 0;
    for (int i = lo; i < hi; ++i) total += cnt[i];
    sdata[t] = total;
    __syncthreads();
    for (int s = SCAN_T / 2; s > 0; s >>= 1) {
        if (t < s) sdata[t] += sdata[t + s];
        __syncthreads();
    }
    if (t == 0) blktot[b] = sdata[0];
}

// ---------------------------------------------------------------------------
// scan pass 2: each block sums blktot[0..b) locally (64 ints, thread 0),
// then writes exclusive scan into off[] and cur[].
// ---------------------------------------------------------------------------
__global__ __launch_bounds__(SCAN_T) void scan_write(
    int* __restrict__ off, int* __restrict__ cur,
    const int* __restrict__ blktot, int N, int E)
{
    __shared__ int sdata[SCAN_T];
    __shared__ int sbase;
    const int t = threadIdx.x, b = blockIdx.x;
    const int chunk = (N + SCAN_B * SCAN_T - 1) / (SCAN_B * SCAN_T);
    const int lo = (b * SCAN_T + t) * chunk;
    const int hi = min(lo + chunk, N);

    if (t == 0) {
        int s = 0;
        for (int i = 0; i < b; ++i) s += blktot[i];
        sbase = s;
    }
    int total = 0;
    for (int i = lo; i < hi; ++i) total += off[i];
    sdata[t] = total;
    __syncthreads();
    for (int s = 1; s < SCAN_T; s <<= 1) {
        int v = (t >= s) ? sdata[t - s] : 0;
        __syncthreads();
        sdata[t] += v;
        __syncthreads();
    }
    int running = sbase + ((t > 0) ? sdata[t - 1] : 0);
    for (int i = lo; i < hi; ++i) {
        int c = off[i];
        off[i] = running;
        cur[i] = running;
        running += c;
    }
    if (b == 0 && t == 0) off[N] = E;
}

// ---------------------------------------------------------------------------
// counting-sort of src by dst bucket
// ---------------------------------------------------------------------------
__global__ __launch_bounds__(256) void sage_sort(
    const int* __restrict__ src, const int* __restrict__ dst,
    int* __restrict__ cur, int* __restrict__ srt, int E)
{
    int e = blockIdx.x * 256 + threadIdx.x;
    if (e < E) {
        int p = atomicAdd(&cur[dst[e]], 1);
        srt[p] = src[e];
    }
}

// ---------------------------------------------------------------------------
// fused gather + gemm:
//   phase 1: wave w gathers means of its 16 nodes (64 lanes/node, one
//            coalesced 256B dword-load per edge, wave-uniform loop) -> LDS
//   phase 2: MFMA 16x16x32 bf16: C = mean@Wl (ks 0..3, A from LDS)
//                               + x@Wr    (ks 4..7, A from global xb)
//   epilogue: out = x + relu(C + bl)
// ---------------------------------------------------------------------------
__global__ __launch_bounds__(256) void sage_gg(
    const char* __restrict__ xb, const int* __restrict__ off,
    const int* __restrict__ srt, const uint4* __restrict__ Bf,
    const float* __restrict__ bl, const float* __restrict__ x,
    float* __restrict__ out, int N)
{
    __shared__ char mlds[GN * MST];
    const int t = threadIdx.x;
    const int wv = t >> 6;
    const int lane = t & 63;
    const int nb0 = blockIdx.x * GN;

    // ---- phase 1: gather means, 16 nodes per wave, serial per node ----
    for (int i = 0; i < 16; ++i) {
        int nl = wv * 16 + i;
        int n = nb0 + nl;
        float a0 = 0.f, a1 = 0.f;
        int deg = 1;
        if (n < N) {
            int start = __builtin_amdgcn_readfirstlane(off[n]);
            int end   = __builtin_amdgcn_readfirstlane(off[n + 1]);
            deg = max(end - start, 1);
            for (int e = start; e < end; ++e) {
                int s = srt[e];   // wave-uniform -> scalar load
                unsigned int v = *(const unsigned int*)(xb + (size_t)s * 256 + (size_t)lane * 4);
                a0 += bf16lo(v);
                a1 += bf16hi(v);
            }
        }
        float inv = 1.0f / (float)deg;
        unsigned int o = bf16rne(a0 * inv) | (bf16rne(a1 * inv) << 16);
        *(unsigned int*)(mlds + nl * MST + lane * 4) = o;
    }
    __syncthreads();

    // ---- phase 2: MFMA ----
    const int q = lane >> 4, m16 = lane & 15;
    const int nb = nb0 + wv * 16;
    const int am = min(nb + m16, N - 1);
    const short8* arow = (const short8*)(xb + (size_t)am * 256);
    const short8* mrow = (const short8*)(mlds + (wv * 16 + m16) * MST);
    const short8* bfp  = (const short8*)Bf;

    float4v acc[8];
    #pragma unroll
    for (int ct = 0; ct < 8; ++ct) acc[ct] = (float4v){0.f, 0.f, 0.f, 0.f};

    #pragma unroll
    for (int ks = 0; ks < 4; ++ks) {          // mean @ Wl
        short8 af = mrow[ks * 4 + q];
        #pragma unroll
        for (int ct = 0; ct < 8; ++ct) {
            short8 bfrag = bfp[(ks * 8 + ct) * 64 + lane];
            acc[ct] = __builtin_amdgcn_mfma_f32_16x16x32_bf16(af, bfrag, acc[ct], 0, 0, 0);
        }
    }
    #pragma unroll
    for (int ks = 0; ks < 4; ++ks) {          // x @ Wr
        short8 af = arow[ks * 4 + q];
        #pragma unroll
        for (int ct = 0; ct < 8; ++ct) {
            short8 bfrag = bfp[((ks + 4) * 8 + ct) * 64 + lane];
            acc[ct] = __builtin_amdgcn_mfma_f32_16x16x32_bf16(af, bfrag, acc[ct], 0, 0, 0);
        }
    }

    // ---- epilogue ----
    #pragma unroll
    for (int ct = 0; ct < 8; ++ct) {
        int col = ct * 16 + m16;
        float b = bl[col];
        #pragma unroll
        for (int r = 0; r < 4; ++r) {
            int n2 = nb + q * 4 + r;
            if (n2 < N) {
                size_t idx = (size_t)n2 * DF + col;
                out[idx] = x[idx] + fmaxf(acc[ct][r] + b, 0.f);
            }
        }
    }
}

extern "C" void kernel_launch(void* const* d_in, const int* in_sizes, int n_in,
                              void* d_out, int out_size, void* d_ws, size_t ws_size,
                              hipStream_t stream) {
    const float* x  = (const float*)d_in[0];
    const int*   ei = (const int*)d_in[1];
    const float* Wl = (const float*)d_in[2];
    const float* bl = (const float*)d_in[3];
    const float* Wr = (const float*)d_in[4];
    float* out = (float*)d_out;

    const int N = in_sizes[0] / DF;
    const int E = in_sizes[1] / 2;
    const int* src = ei;
    const int* dst = ei + E;

    // ws: off[N+1] | cur[N] | srt[E] | blktot[64] | pad16 | Bf[4096*16B] | xb[N*256B]
    int* off    = (int*)d_ws;
    int* cur    = off + (N + 1);
    int* srt    = cur + N;
    int* blktot = srt + E;
    size_t bfoff = ((size_t)(N + 1 + N + E + 64) * 4 + 15) & ~(size_t)15;
    uint4* Bf   = (uint4*)((char*)d_ws + bfoff);
    char* xb    = (char*)d_ws + bfoff + 4096 * 16;

    hipMemsetAsync(off, 0, (size_t)(N + 1) * sizeof(int), stream);

    int prepT = N * 16;                     // covers xcast range (> E, > 4096)
    sage_prep<<<(prepT + 255) / 256, 256, 0, stream>>>(
        x, dst, Wl, Wr, off, xb, Bf, N, E);
    scan_reduce<<<SCAN_B, SCAN_T, 0, stream>>>(off, blktot, N);
    scan_write<<<SCAN_B, SCAN_T, 0, stream>>>(off, cur, blktot, N, E);
    sage_sort<<<(E + 255) / 256, 256, 0, stream>>>(src, dst, cur, srt, E);
    sage_gg<<<(N + GN - 1) / GN, 256, 0, stream>>>(
        xb, off, srt, Bf, bl, x, out, N);
}

// Round 6
// 205.717 us; speedup vs baseline: 1.2028x; 1.2028x over previous
//
#include <hip/hip_runtime.h>

#define DF 128
#define SCAN_B 64
#define SCAN_T 256
#define GN 64           // nodes per gather_gemm block
#define MST 272         // LDS mean-row stride bytes (17*16)

typedef __attribute__((ext_vector_type(8))) short short8;
typedef __attribute__((ext_vector_type(4))) float float4v;

__device__ __forceinline__ unsigned int bf16rne(float f) {
    unsigned int u = __float_as_uint(f);
    return (u + 0x7fffu + ((u >> 16) & 1u)) >> 16;
}
__device__ __forceinline__ float bf16lo(unsigned int w) {
    return __uint_as_float(w << 16);
}
__device__ __forceinline__ float bf16hi(unsigned int w) {
    return __uint_as_float(w & 0xffff0000u);
}

// ---------------------------------------------------------------------------
// prep: fused (a) histogram of dst, (b) x fp32->bf16 cast into compact xb,
// (c) [Wl;Wr] swizzle into MFMA B-fragment order (bf16).
// ---------------------------------------------------------------------------
__global__ __launch_bounds__(256) void sage_prep(
    const float* __restrict__ x, const int* __restrict__ dst,
    const float* __restrict__ Wl, const float* __restrict__ Wr,
    int* __restrict__ cnt, char* __restrict__ xb, uint4* __restrict__ Bf,
    int N, int E)
{
    int tid = blockIdx.x * 256 + threadIdx.x;

    if (tid < N * 16) {                      // xcast: 16 threads/row
        int n = tid >> 4;
        int c = (tid & 15) * 8;
        const float4* xp = (const float4*)&x[(size_t)n * DF + c];
        float4 a = xp[0], b = xp[1];
        uint4 o;
        o.x = bf16rne(a.x) | (bf16rne(a.y) << 16);
        o.y = bf16rne(a.z) | (bf16rne(a.w) << 16);
        o.z = bf16rne(b.x) | (bf16rne(b.y) << 16);
        o.w = bf16rne(b.z) | (bf16rne(b.w) << 16);
        *(uint4*)(xb + (size_t)n * 256 + (size_t)(tid & 15) * 16) = o;
    }

    if (tid < E) atomicAdd(&cnt[dst[tid]], 1);   // histogram

    if (tid < 4096) {                        // bprep
        int lane = tid & 63;
        int ctks = tid >> 6;
        int ks = ctks >> 3, ct = ctks & 7;
        int q = lane >> 4, m16 = lane & 15;
        int n = ct * 16 + m16;
        unsigned int w[4];
        #pragma unroll
        for (int p = 0; p < 4; ++p) {
            int k0 = ks * 32 + q * 8 + p * 2;
            float f0 = (k0 < DF) ? Wl[k0 * DF + n] : Wr[(k0 - DF) * DF + n];
            float f1 = (k0 + 1 < DF) ? Wl[(k0 + 1) * DF + n] : Wr[(k0 + 1 - DF) * DF + n];
            w[p] = bf16rne(f0) | (bf16rne(f1) << 16);
        }
        uint4 o = {w[0], w[1], w[2], w[3]};
        Bf[tid] = o;
    }
}

// ---------------------------------------------------------------------------
// scan pass 1: per-block reduce -> blktot
// ---------------------------------------------------------------------------
__global__ __launch_bounds__(SCAN_T) void scan_reduce(
    const int* __restrict__ cnt, int* __restrict__ blktot, int N)
{
    __shared__ int sdata[SCAN_T];
    const int t = threadIdx.x, b = blockIdx.x;
    const int chunk = (N + SCAN_B * SCAN_T - 1) / (SCAN_B * SCAN_T);
    const int lo = (b * SCAN_T + t) * chunk;
    const int hi = min(lo + chunk, N);
    int total = 0;
    for (int i = lo; i < hi; ++i) total += cnt[i];
    sdata[t] = total;
    __syncthreads();
    for (int s = SCAN_T / 2; s > 0; s >>= 1) {
        if (t < s) sdata[t] += sdata[t + s];
        __syncthreads();
    }
    if (t == 0) blktot[b] = sdata[0];
}

// ---------------------------------------------------------------------------
// scan pass 2: block-local base (64 serial adds on t0) + LDS scan + write
// ---------------------------------------------------------------------------
__global__ __launch_bounds__(SCAN_T) void scan_write(
    int* __restrict__ off, int* __restrict__ cur,
    const int* __restrict__ blktot, int N, int E)
{
    __shared__ int sdata[SCAN_T];
    __shared__ int sbase;
    const int t = threadIdx.x, b = blockIdx.x;
    const int chunk = (N + SCAN_B * SCAN_T - 1) / (SCAN_B * SCAN_T);
    const int lo = (b * SCAN_T + t) * chunk;
    const int hi = min(lo + chunk, N);

    if (t == 0) {
        int s = 0;
        for (int i = 0; i < b; ++i) s += blktot[i];
        sbase = s;
    }
    int total = 0;
    for (int i = lo; i < hi; ++i) total += off[i];
    sdata[t] = total;
    __syncthreads();
    for (int s = 1; s < SCAN_T; s <<= 1) {
        int v = (t >= s) ? sdata[t - s] : 0;
        __syncthreads();
        sdata[t] += v;
        __syncthreads();
    }
    int running = sbase + ((t > 0) ? sdata[t - 1] : 0);
    for (int i = lo; i < hi; ++i) {
        int c = off[i];
        off[i] = running;
        cur[i] = running;
        running += c;
    }
    if (b == 0 && t == 0) off[N] = E;
}

// ---------------------------------------------------------------------------
// counting-sort of src by dst bucket
// ---------------------------------------------------------------------------
__global__ __launch_bounds__(256) void sage_sort(
    const int* __restrict__ src, const int* __restrict__ dst,
    int* __restrict__ cur, int* __restrict__ srt, int E)
{
    int e = blockIdx.x * 256 + threadIdx.x;
    if (e < E) {
        int p = atomicAdd(&cur[dst[e]], 1);
        srt[p] = src[e];
    }
}

// ---------------------------------------------------------------------------
// fused gather + gemm:
//   phase 1: 16 node-groups x 16 lanes in parallel; lane owns 16B of the
//            row; edge loop unrolled x4 (4 independent uint4 loads in
//            flight). Means -> LDS (bf16).
//   phase 2: MFMA 16x16x32 bf16: C = mean@Wl + x@Wr (B pre-swizzled)
//   epilogue: out = x + relu(C + bl)
// ---------------------------------------------------------------------------
__global__ __launch_bounds__(256) void sage_gg(
    const char* __restrict__ xb, const int* __restrict__ off,
    const int* __restrict__ srt, const uint4* __restrict__ Bf,
    const float* __restrict__ bl, const float* __restrict__ x,
    float* __restrict__ out, int N)
{
    __shared__ char mlds[GN * MST];
    const int t = threadIdx.x;
    const int nb0 = blockIdx.x * GN;

    // ---- phase 1: 16 lanes per node, 16 nodes concurrent, 4 rounds ----
    {
        const int ln = t & 15;              // lane within node group
        const int g  = t >> 4;              // node group 0..15
        const size_t lnb = (size_t)ln * 16; // byte offset within row

        #pragma unroll
        for (int i = 0; i < GN / 16; ++i) {
            int nl = i * 16 + g;
            int n = nb0 + nl;
            float a0 = 0.f, a1 = 0.f, a2 = 0.f, a3 = 0.f;
            float a4 = 0.f, a5 = 0.f, a6 = 0.f, a7 = 0.f;
            int deg = 1;
            if (n < N) {
                int start = off[n];
                int end   = off[n + 1];
                deg = max(end - start, 1);
                int e = start;
                for (; e + 4 <= end; e += 4) {
                    int s0 = srt[e + 0], s1 = srt[e + 1];
                    int s2 = srt[e + 2], s3 = srt[e + 3];
                    uint4 v0 = *(const uint4*)(xb + (size_t)s0 * 256 + lnb);
                    uint4 v1 = *(const uint4*)(xb + (size_t)s1 * 256 + lnb);
                    uint4 v2 = *(const uint4*)(xb + (size_t)s2 * 256 + lnb);
                    uint4 v3 = *(const uint4*)(xb + (size_t)s3 * 256 + lnb);
                    a0 += bf16lo(v0.x); a1 += bf16hi(v0.x);
                    a2 += bf16lo(v0.y); a3 += bf16hi(v0.y);
                    a4 += bf16lo(v0.z); a5 += bf16hi(v0.z);
                    a6 += bf16lo(v0.w); a7 += bf16hi(v0.w);
                    a0 += bf16lo(v1.x); a1 += bf16hi(v1.x);
                    a2 += bf16lo(v1.y); a3 += bf16hi(v1.y);
                    a4 += bf16lo(v1.z); a5 += bf16hi(v1.z);
                    a6 += bf16lo(v1.w); a7 += bf16hi(v1.w);
                    a0 += bf16lo(v2.x); a1 += bf16hi(v2.x);
                    a2 += bf16lo(v2.y); a3 += bf16hi(v2.y);
                    a4 += bf16lo(v2.z); a5 += bf16hi(v2.z);
                    a6 += bf16lo(v2.w); a7 += bf16hi(v2.w);
                    a0 += bf16lo(v3.x); a1 += bf16hi(v3.x);
                    a2 += bf16lo(v3.y); a3 += bf16hi(v3.y);
                    a4 += bf16lo(v3.z); a5 += bf16hi(v3.z);
                    a6 += bf16lo(v3.w); a7 += bf16hi(v3.w);
                }
                for (; e < end; ++e) {
                    int s = srt[e];
                    uint4 v = *(const uint4*)(xb + (size_t)s * 256 + lnb);
                    a0 += bf16lo(v.x); a1 += bf16hi(v.x);
                    a2 += bf16lo(v.y); a3 += bf16hi(v.y);
                    a4 += bf16lo(v.z); a5 += bf16hi(v.z);
                    a6 += bf16lo(v.w); a7 += bf16hi(v.w);
                }
            }
            float inv = 1.0f / (float)deg;
            uint4 o;
            o.x = bf16rne(a0 * inv) | (bf16rne(a1 * inv) << 16);
            o.y = bf16rne(a2 * inv) | (bf16rne(a3 * inv) << 16);
            o.z = bf16rne(a4 * inv) | (bf16rne(a5 * inv) << 16);
            o.w = bf16rne(a6 * inv) | (bf16rne(a7 * inv) << 16);
            *(uint4*)(mlds + nl * MST + ln * 16) = o;
        }
    }
    __syncthreads();

    // ---- phase 2: MFMA ----
    const int wv = t >> 6;
    const int lane = t & 63;
    const int q = lane >> 4, m16 = lane & 15;
    const int nb = nb0 + wv * 16;
    const int am = min(nb + m16, N - 1);
    const short8* arow = (const short8*)(xb + (size_t)am * 256);
    const short8* mrow = (const short8*)(mlds + (wv * 16 + m16) * MST);
    const short8* bfp  = (const short8*)Bf;

    float4v acc[8];
    #pragma unroll
    for (int ct = 0; ct < 8; ++ct) acc[ct] = (float4v){0.f, 0.f, 0.f, 0.f};

    #pragma unroll
    for (int ks = 0; ks < 4; ++ks) {          // mean @ Wl
        short8 af = mrow[ks * 4 + q];
        #pragma unroll
        for (int ct = 0; ct < 8; ++ct) {
            short8 bfrag = bfp[(ks * 8 + ct) * 64 + lane];
            acc[ct] = __builtin_amdgcn_mfma_f32_16x16x32_bf16(af, bfrag, acc[ct], 0, 0, 0);
        }
    }
    #pragma unroll
    for (int ks = 0; ks < 4; ++ks) {          // x @ Wr
        short8 af = arow[ks * 4 + q];
        #pragma unroll
        for (int ct = 0; ct < 8; ++ct) {
            short8 bfrag = bfp[((ks + 4) * 8 + ct) * 64 + lane];
            acc[ct] = __builtin_amdgcn_mfma_f32_16x16x32_bf16(af, bfrag, acc[ct], 0, 0, 0);
        }
    }

    // ---- epilogue ----
    #pragma unroll
    for (int ct = 0; ct < 8; ++ct) {
        int col = ct * 16 + m16;
        float b = bl[col];
        #pragma unroll
        for (int r = 0; r < 4; ++r) {
            int n2 = nb + q * 4 + r;
            if (n2 < N) {
                size_t idx = (size_t)n2 * DF + col;
                out[idx] = x[idx] + fmaxf(acc[ct][r] + b, 0.f);
            }
        }
    }
}

extern "C" void kernel_launch(void* const* d_in, const int* in_sizes, int n_in,
                              void* d_out, int out_size, void* d_ws, size_t ws_size,
                              hipStream_t stream) {
    const float* x  = (const float*)d_in[0];
    const int*   ei = (const int*)d_in[1];
    const float* Wl = (const float*)d_in[2];
    const float* bl = (const float*)d_in[3];
    const float* Wr = (const float*)d_in[4];
    float* out = (float*)d_out;

    const int N = in_sizes[0] / DF;
    const int E = in_sizes[1] / 2;
    const int* src = ei;
    const int* dst = ei + E;

    // ws: off[N+1] | cur[N] | srt[E] | blktot[64] | pad16 | Bf[4096*16B] | xb[N*256B]
    int* off    = (int*)d_ws;
    int* cur    = off + (N + 1);
    int* srt    = cur + N;
    int* blktot = srt + E;
    size_t bfoff = ((size_t)(N + 1 + N + E + 64) * 4 + 15) & ~(size_t)15;
    uint4* Bf   = (uint4*)((char*)d_ws + bfoff);
    char* xb    = (char*)d_ws + bfoff + 4096 * 16;

    hipMemsetAsync(off, 0, (size_t)(N + 1) * sizeof(int), stream);

    int prepT = N * 16;
    sage_prep<<<(prepT + 255) / 256, 256, 0, stream>>>(
        x, dst, Wl, Wr, off, xb, Bf, N, E);
    scan_reduce<<<SCAN_B, SCAN_T, 0, stream>>>(off, blktot, N);
    scan_write<<<SCAN_B, SCAN_T, 0, stream>>>(off, cur, blktot, N, E);
    sage_sort<<<(E + 255) / 256, 256, 0, stream>>>(src, dst, cur, srt, E);
    sage_gg<<<(N + GN - 1) / GN, 256, 0, stream>>>(
        xb, off, srt, Bf, bl, x, out, N);
}

// Round 7
// 200.184 us; speedup vs baseline: 1.2361x; 1.0276x over previous
//
#include <hip/hip_runtime.h>

#define DF 128
#define SCAN_B 64
#define SCAN_T 256
#define GN 32           // nodes per gather_gemm block
#define MST 272         // LDS mean-row stride bytes (17*16)

typedef __attribute__((ext_vector_type(8))) short short8;
typedef __attribute__((ext_vector_type(4))) float float4v;

__device__ __forceinline__ unsigned int bf16rne(float f) {
    unsigned int u = __float_as_uint(f);
    return (u + 0x7fffu + ((u >> 16) & 1u)) >> 16;
}
__device__ __forceinline__ float bf16lo(unsigned int w) {
    return __uint_as_float(w << 16);
}
__device__ __forceinline__ float bf16hi(unsigned int w) {
    return __uint_as_float(w & 0xffff0000u);
}

// ---------------------------------------------------------------------------
// prep: fused (a) histogram of dst, (b) x fp32->bf16 cast into compact xb,
// (c) [Wl;Wr] swizzle into MFMA B-fragment order (bf16).
// ---------------------------------------------------------------------------
__global__ __launch_bounds__(256) void sage_prep(
    const float* __restrict__ x, const int* __restrict__ dst,
    const float* __restrict__ Wl, const float* __restrict__ Wr,
    int* __restrict__ cnt, char* __restrict__ xb, uint4* __restrict__ Bf,
    int N, int E)
{
    int tid = blockIdx.x * 256 + threadIdx.x;

    if (tid < N * 16) {                      // xcast: 16 threads/row
        int n = tid >> 4;
        int c = (tid & 15) * 8;
        const float4* xp = (const float4*)&x[(size_t)n * DF + c];
        float4 a = xp[0], b = xp[1];
        uint4 o;
        o.x = bf16rne(a.x) | (bf16rne(a.y) << 16);
        o.y = bf16rne(a.z) | (bf16rne(a.w) << 16);
        o.z = bf16rne(b.x) | (bf16rne(b.y) << 16);
        o.w = bf16rne(b.z) | (bf16rne(b.w) << 16);
        *(uint4*)(xb + (size_t)n * 256 + (size_t)(tid & 15) * 16) = o;
    }

    if (tid < E) atomicAdd(&cnt[dst[tid]], 1);   // histogram

    if (tid < 4096) {                        // bprep
        int lane = tid & 63;
        int ctks = tid >> 6;
        int ks = ctks >> 3, ct = ctks & 7;
        int q = lane >> 4, m16 = lane & 15;
        int n = ct * 16 + m16;
        unsigned int w[4];
        #pragma unroll
        for (int p = 0; p < 4; ++p) {
            int k0 = ks * 32 + q * 8 + p * 2;
            float f0 = (k0 < DF) ? Wl[k0 * DF + n] : Wr[(k0 - DF) * DF + n];
            float f1 = (k0 + 1 < DF) ? Wl[(k0 + 1) * DF + n] : Wr[(k0 + 1 - DF) * DF + n];
            w[p] = bf16rne(f0) | (bf16rne(f1) << 16);
        }
        uint4 o = {w[0], w[1], w[2], w[3]};
        Bf[tid] = o;
    }
}

// ---------------------------------------------------------------------------
// scan pass 1: per-block reduce -> blktot
// ---------------------------------------------------------------------------
__global__ __launch_bounds__(SCAN_T) void scan_reduce(
    const int* __restrict__ cnt, int* __restrict__ blktot, int N)
{
    __shared__ int sdata[SCAN_T];
    const int t = threadIdx.x, b = blockIdx.x;
    const int chunk = (N + SCAN_B * SCAN_T - 1) / (SCAN_B * SCAN_T);
    const int lo = (b * SCAN_T + t) * chunk;
    const int hi = min(lo + chunk, N);
    int total = 0;
    for (int i = lo; i < hi; ++i) total += cnt[i];
    sdata[t] = total;
    __syncthreads();
    for (int s = SCAN_T / 2; s > 0; s >>= 1) {
        if (t < s) sdata[t] += sdata[t + s];
        __syncthreads();
    }
    if (t == 0) blktot[b] = sdata[0];
}

// ---------------------------------------------------------------------------
// scan pass 2: block-local base (64 serial adds on t0) + LDS scan + write
// ---------------------------------------------------------------------------
__global__ __launch_bounds__(SCAN_T) void scan_write(
    int* __restrict__ off, int* __restrict__ cur,
    const int* __restrict__ blktot, int N, int E)
{
    __shared__ int sdata[SCAN_T];
    __shared__ int sbase;
    const int t = threadIdx.x, b = blockIdx.x;
    const int chunk = (N + SCAN_B * SCAN_T - 1) / (SCAN_B * SCAN_T);
    const int lo = (b * SCAN_T + t) * chunk;
    const int hi = min(lo + chunk, N);

    if (t == 0) {
        int s = 0;
        for (int i = 0; i < b; ++i) s += blktot[i];
        sbase = s;
    }
    int total = 0;
    for (int i = lo; i < hi; ++i) total += off[i];
    sdata[t] = total;
    __syncthreads();
    for (int s = 1; s < SCAN_T; s <<= 1) {
        int v = (t >= s) ? sdata[t - s] : 0;
        __syncthreads();
        sdata[t] += v;
        __syncthreads();
    }
    int running = sbase + ((t > 0) ? sdata[t - 1] : 0);
    for (int i = lo; i < hi; ++i) {
        int c = off[i];
        off[i] = running;
        cur[i] = running;
        running += c;
    }
    if (b == 0 && t == 0) off[N] = E;
}

// ---------------------------------------------------------------------------
// counting-sort of src by dst bucket
// ---------------------------------------------------------------------------
__global__ __launch_bounds__(256) void sage_sort(
    const int* __restrict__ src, const int* __restrict__ dst,
    int* __restrict__ cur, int* __restrict__ srt, int E)
{
    int e = blockIdx.x * 256 + threadIdx.x;
    if (e < E) {
        int p = atomicAdd(&cur[dst[e]], 1);
        srt[p] = src[e];
    }
}

// ---------------------------------------------------------------------------
// fused gather + gemm, GN=32 nodes/block (2x grid vs GN=64 for latency hiding):
//   phase 1: 16 node-groups x 16 lanes; lane owns 16B of row; edge loop
//            unrolled x8 (8 outstanding uint4 loads). Means -> LDS bf16.
//   phase 2: 4 waves = (node-half h, ct-half) pairs; MFMA 16x16x32 bf16.
//   epilogue: out = x + relu(C + bl)   (disjoint (h, ct) -> no overlap)
// ---------------------------------------------------------------------------
__global__ __launch_bounds__(256) void sage_gg(
    const char* __restrict__ xb, const int* __restrict__ off,
    const int* __restrict__ srt, const uint4* __restrict__ Bf,
    const float* __restrict__ bl, const float* __restrict__ x,
    float* __restrict__ out, int N)
{
    __shared__ char mlds[GN * MST];
    const int t = threadIdx.x;
    const int nb0 = blockIdx.x * GN;

    // ---- phase 1: 16 lanes per node, 16 nodes concurrent, 2 rounds ----
    {
        const int ln = t & 15;
        const int g  = t >> 4;
        const size_t lnb = (size_t)ln * 16;

        #pragma unroll
        for (int i = 0; i < GN / 16; ++i) {
            int nl = i * 16 + g;
            int n = nb0 + nl;
            float a0 = 0.f, a1 = 0.f, a2 = 0.f, a3 = 0.f;
            float a4 = 0.f, a5 = 0.f, a6 = 0.f, a7 = 0.f;
            int deg = 1;
            if (n < N) {
                int start = off[n];
                int end   = off[n + 1];
                deg = max(end - start, 1);
                int e = start;
                for (; e + 8 <= end; e += 8) {
                    uint4 v[8];
                    #pragma unroll
                    for (int j = 0; j < 8; ++j) {
                        int s = srt[e + j];
                        v[j] = *(const uint4*)(xb + (size_t)s * 256 + lnb);
                    }
                    #pragma unroll
                    for (int j = 0; j < 8; ++j) {
                        a0 += bf16lo(v[j].x); a1 += bf16hi(v[j].x);
                        a2 += bf16lo(v[j].y); a3 += bf16hi(v[j].y);
                        a4 += bf16lo(v[j].z); a5 += bf16hi(v[j].z);
                        a6 += bf16lo(v[j].w); a7 += bf16hi(v[j].w);
                    }
                }
                if (e + 4 <= end) {
                    uint4 v[4];
                    #pragma unroll
                    for (int j = 0; j < 4; ++j) {
                        int s = srt[e + j];
                        v[j] = *(const uint4*)(xb + (size_t)s * 256 + lnb);
                    }
                    #pragma unroll
                    for (int j = 0; j < 4; ++j) {
                        a0 += bf16lo(v[j].x); a1 += bf16hi(v[j].x);
                        a2 += bf16lo(v[j].y); a3 += bf16hi(v[j].y);
                        a4 += bf16lo(v[j].z); a5 += bf16hi(v[j].z);
                        a6 += bf16lo(v[j].w); a7 += bf16hi(v[j].w);
                    }
                    e += 4;
                }
                for (; e < end; ++e) {
                    int s = srt[e];
                    uint4 v = *(const uint4*)(xb + (size_t)s * 256 + lnb);
                    a0 += bf16lo(v.x); a1 += bf16hi(v.x);
                    a2 += bf16lo(v.y); a3 += bf16hi(v.y);
                    a4 += bf16lo(v.z); a5 += bf16hi(v.z);
                    a6 += bf16lo(v.w); a7 += bf16hi(v.w);
                }
            }
            float inv = 1.0f / (float)deg;
            uint4 o;
            o.x = bf16rne(a0 * inv) | (bf16rne(a1 * inv) << 16);
            o.y = bf16rne(a2 * inv) | (bf16rne(a3 * inv) << 16);
            o.z = bf16rne(a4 * inv) | (bf16rne(a5 * inv) << 16);
            o.w = bf16rne(a6 * inv) | (bf16rne(a7 * inv) << 16);
            *(uint4*)(mlds + nl * MST + ln * 16) = o;
        }
    }
    __syncthreads();

    // ---- phase 2: MFMA; wave = (node-half h, ct-half cth) ----
    const int wv = t >> 6;
    const int lane = t & 63;
    const int h   = wv & 1;
    const int cth = wv >> 1;
    const int q = lane >> 4, m16 = lane & 15;
    const int nb = nb0 + h * 16;
    const int am = min(nb + m16, N - 1);
    const short8* arow = (const short8*)(xb + (size_t)am * 256);
    const short8* mrow = (const short8*)(mlds + (h * 16 + m16) * MST);
    const short8* bfp  = (const short8*)Bf;

    float4v acc[4];
    #pragma unroll
    for (int c4 = 0; c4 < 4; ++c4) acc[c4] = (float4v){0.f, 0.f, 0.f, 0.f};

    #pragma unroll
    for (int ks = 0; ks < 4; ++ks) {          // mean @ Wl
        short8 af = mrow[ks * 4 + q];
        #pragma unroll
        for (int c4 = 0; c4 < 4; ++c4) {
            int ct = cth * 4 + c4;
            short8 bfrag = bfp[(ks * 8 + ct) * 64 + lane];
            acc[c4] = __builtin_amdgcn_mfma_f32_16x16x32_bf16(af, bfrag, acc[c4], 0, 0, 0);
        }
    }
    #pragma unroll
    for (int ks = 0; ks < 4; ++ks) {          // x @ Wr
        short8 af = arow[ks * 4 + q];
        #pragma unroll
        for (int c4 = 0; c4 < 4; ++c4) {
            int ct = cth * 4 + c4;
            short8 bfrag = bfp[((ks + 4) * 8 + ct) * 64 + lane];
            acc[c4] = __builtin_amdgcn_mfma_f32_16x16x32_bf16(af, bfrag, acc[c4], 0, 0, 0);
        }
    }

    // ---- epilogue ----
    #pragma unroll
    for (int c4 = 0; c4 < 4; ++c4) {
        int col = (cth * 4 + c4) * 16 + m16;
        float b = bl[col];
        #pragma unroll
        for (int r = 0; r < 4; ++r) {
            int n2 = nb + q * 4 + r;
            if (n2 < N) {
                size_t idx = (size_t)n2 * DF + col;
                out[idx] = x[idx] + fmaxf(acc[c4][r] + b, 0.f);
            }
        }
    }
}

extern "C" void kernel_launch(void* const* d_in, const int* in_sizes, int n_in,
                              void* d_out, int out_size, void* d_ws, size_t ws_size,
                              hipStream_t stream) {
    const float* x  = (const float*)d_in[0];
    const int*   ei = (const int*)d_in[1];
    const float* Wl = (const float*)d_in[2];
    const float* bl = (const float*)d_in[3];
    const float* Wr = (const float*)d_in[4];
    float* out = (float*)d_out;

    const int N = in_sizes[0] / DF;
    const int E = in_sizes[1] / 2;
    const int* src = ei;
    const int* dst = ei + E;

    // ws: off[N+1] | cur[N] | srt[E] | blktot[64] | pad16 | Bf[4096*16B] | xb[N*256B]
    int* off    = (int*)d_ws;
    int* cur    = off + (N + 1);
    int* srt    = cur + N;
    int* blktot = srt + E;
    size_t bfoff = ((size_t)(N + 1 + N + E + 64) * 4 + 15) & ~(size_t)15;
    uint4* Bf   = (uint4*)((char*)d_ws + bfoff);
    char* xb    = (char*)d_ws + bfoff + 4096 * 16;

    hipMemsetAsync(off, 0, (size_t)(N + 1) * sizeof(int), stream);

    int prepT = N * 16;
    sage_prep<<<(prepT + 255) / 256, 256, 0, stream>>>(
        x, dst, Wl, Wr, off, xb, Bf, N, E);
    scan_reduce<<<SCAN_B, SCAN_T, 0, stream>>>(off, blktot, N);
    scan_write<<<SCAN_B, SCAN_T, 0, stream>>>(off, cur, blktot, N, E);
    sage_sort<<<(E + 255) / 256, 256, 0, stream>>>(src, dst, cur, srt, E);
    sage_gg<<<(N + GN - 1) / GN, 256, 0, stream>>>(
        xb, off, srt, Bf, bl, x, out, N);
}